// Round 11
// baseline (1797.868 us; speedup 1.0000x reference)
//
#include <hip/hip_runtime.h>
#include <stdint.h>

#define DEV static __device__ __forceinline__

typedef int v4i __attribute__((ext_vector_type(4)));
typedef short v8s __attribute__((ext_vector_type(8)));
typedef float v4f __attribute__((ext_vector_type(4)));
typedef unsigned short u16x8 __attribute__((ext_vector_type(8)));

constexpr int B_T   = 8192;
constexpr int IN_D  = 1024;
constexpr int H1D   = 2048;
constexpr int H2D   = 2048;
constexpr int CDIM  = 1000;
constexpr int NEXP  = 8;
constexpr int RHD   = 512;
constexpr float QBF  = 127.0f;
constexpr float EPSF = 1e-5f;
constexpr int NSLOT = 2 * B_T;
constexpr int MAXT  = 72;
constexpr float GAP_DELTA = 2e-3f;

DEV void load_lds16(const void* g, void* l) {
  __builtin_amdgcn_global_load_lds(
      (const __attribute__((address_space(1))) uint32_t*)(uintptr_t)g,
      (__attribute__((address_space(3))) uint32_t*)(uint32_t)(uintptr_t)l,
      16, 0, 0);
}

DEV uint32_t pack4(float a, float b, float c, float d, float s) {
  int q0 = (int)rintf(a * s); q0 = q0 > 127 ? 127 : (q0 < -127 ? -127 : q0);
  int q1 = (int)rintf(b * s); q1 = q1 > 127 ? 127 : (q1 < -127 ? -127 : q1);
  int q2 = (int)rintf(c * s); q2 = q2 > 127 ? 127 : (q2 < -127 ? -127 : q2);
  int q3 = (int)rintf(d * s); q3 = q3 > 127 ? 127 : (q3 < -127 ? -127 : q3);
  return (uint32_t)(uint8_t)q0 | ((uint32_t)(uint8_t)q1 << 8) |
         ((uint32_t)(uint8_t)q2 << 16) | ((uint32_t)(uint8_t)q3 << 24);
}

DEV uint16_t f2bf(float f) {
  uint32_t u = __float_as_uint(f);
  return (uint16_t)((u + 0x7FFFu + ((u >> 16) & 1u)) >> 16);
}
DEV float bf2f(uint16_t h) { return __uint_as_float((uint32_t)h << 16); }

// ---- slice helper: t in [0,24) -> tensor/expert slice -----------------------
DEV const float* slice_base(int t, const float* W1, const float* W2, const float* W3,
                            long& n4) {
  const float* W; long perExpert;
  if (t < 8)       { W = W1; perExpert = (long)H1D * IN_D; }
  else if (t < 16) { W = W2; perExpert = (long)H2D * H1D; }
  else             { W = W3; perExpert = (long)CDIM * H2D; }
  n4 = perExpert >> 2;
  return W + (long)(t & 7) * perExpert;
}

// ---------------- weight |.| mean reduction (ILP-4, one launch) --------------
__global__ __launch_bounds__(256) void wabs_all(const float* __restrict__ W1,
                                                const float* __restrict__ W2,
                                                const float* __restrict__ W3,
                                                double* __restrict__ partial) {
  const int t = blockIdx.y;
  long n4;
  const float4* base = (const float4*)slice_base(t, W1, W2, W3, n4);
  double s0 = 0.0, s1 = 0.0, s2 = 0.0, s3 = 0.0;
  const long stride4 = 64L * 256L * 4L;
  for (long i4 = ((long)blockIdx.x * 256 + threadIdx.x) * 4; i4 < n4; i4 += stride4) {
    float4 a = base[i4 + 0];
    float4 b = base[i4 + 1];
    float4 c = base[i4 + 2];
    float4 d = base[i4 + 3];
    s0 += (double)fabsf(a.x) + (double)fabsf(a.y) + (double)fabsf(a.z) + (double)fabsf(a.w);
    s1 += (double)fabsf(b.x) + (double)fabsf(b.y) + (double)fabsf(b.z) + (double)fabsf(b.w);
    s2 += (double)fabsf(c.x) + (double)fabsf(c.y) + (double)fabsf(c.z) + (double)fabsf(c.w);
    s3 += (double)fabsf(d.x) + (double)fabsf(d.y) + (double)fabsf(d.z) + (double)fabsf(d.w);
  }
  __shared__ double red[256];
  red[threadIdx.x] = (s0 + s1) + (s2 + s3);
  __syncthreads();
  for (int st = 128; st > 0; st >>= 1) {
    if ((int)threadIdx.x < st) red[threadIdx.x] += red[threadIdx.x + st];
    __syncthreads();
  }
  if (threadIdx.x == 0) partial[(long)t * 64 + blockIdx.x] = red[0];
}

__global__ void finalize_scales(const double* __restrict__ partial, float* __restrict__ swf) {
  int t = threadIdx.x;
  if (t >= 24) return;
  double s = 0.0;
  for (int i = 0; i < 64; ++i) s += partial[t * 64 + i];
  long cnt = (t < 8) ? (long)H1D * IN_D : (t < 16) ? (long)H2D * H1D : (long)CDIM * H2D;
  float mean = (float)(s / (double)cnt);
  swf[t] = fmaxf(mean, EPSF);
}

// ---------------- ternary weight quantization (all slices, ILP-4) ------------
__global__ __launch_bounds__(256) void wquant_all(const float* __restrict__ W1,
                                                  const float* __restrict__ W2,
                                                  const float* __restrict__ W3,
                                                  int8_t* __restrict__ wq1,
                                                  int8_t* __restrict__ wq2,
                                                  int8_t* __restrict__ wq3,
                                                  const float* __restrict__ swf) {
  const int t = blockIdx.y;
  long n4;
  const float4* base = (const float4*)slice_base(t, W1, W2, W3, n4);
  int8_t* Wq = (t < 8) ? wq1 : (t < 16) ? wq2 : wq3;
  uint32_t* out = (uint32_t*)(Wq) + (long)(t & 7) * n4;
  const float s = swf[t];
  const long stride4 = 64L * 256L * 4L;
  for (long i4 = ((long)blockIdx.x * 256 + threadIdx.x) * 4; i4 < n4; i4 += stride4) {
#pragma unroll
    for (int j = 0; j < 4; ++j) {
      float4 v = base[i4 + j];
      float t0 = fminf(fmaxf(rintf(v.x / s), -1.f), 1.f);
      float t1 = fminf(fmaxf(rintf(v.y / s), -1.f), 1.f);
      float t2 = fminf(fmaxf(rintf(v.z / s), -1.f), 1.f);
      float t3 = fminf(fmaxf(rintf(v.w / s), -1.f), 1.f);
      out[i4 + j] = (uint32_t)(uint8_t)(int8_t)t0 | ((uint32_t)(uint8_t)(int8_t)t1 << 8) |
                    ((uint32_t)(uint8_t)(int8_t)t2 << 16) | ((uint32_t)(uint8_t)(int8_t)t3 << 24);
    }
  }
}

// ---------------- x: fused absmax-quant + bf16 hi/lo split -------------------
__global__ __launch_bounds__(256) void actquant_split(const float* __restrict__ X,
                                                      int8_t* __restrict__ Xq,
                                                      float* __restrict__ rcp_out,
                                                      uint16_t* __restrict__ xh,
                                                      uint16_t* __restrict__ xl) {
  const int row = blockIdx.x;
  const int tid = threadIdx.x;
  float4 v = ((const float4*)(X + (size_t)row * IN_D))[tid];
  float mx = fmaxf(fmaxf(fabsf(v.x), fabsf(v.y)), fmaxf(fabsf(v.z), fabsf(v.w)));
#pragma unroll
  for (int m = 1; m < 64; m <<= 1) mx = fmaxf(mx, __shfl_xor(mx, m));
  __shared__ float wmax[4];
  const int lane = tid & 63, w = tid >> 6;
  if (lane == 0) wmax[w] = mx;
  __syncthreads();
  mx = fmaxf(fmaxf(wmax[0], wmax[1]), fmaxf(wmax[2], wmax[3]));
  const float M = fmaxf(mx, EPSF);
  const float s = QBF / M;
  ((uint32_t*)(Xq + (size_t)row * IN_D))[tid] = pack4(v.x, v.y, v.z, v.w, s);
  if (tid == 0) rcp_out[row] = M / QBF;
  float f[4] = {v.x, v.y, v.z, v.w};
  ushort4 hh, ll;
  uint16_t h4[4], l4[4];
#pragma unroll
  for (int j = 0; j < 4; ++j) {
    h4[j] = f2bf(f[j]);
    l4[j] = f2bf(f[j] - bf2f(h4[j]));
  }
  hh.x = h4[0]; hh.y = h4[1]; hh.z = h4[2]; hh.w = h4[3];
  ll.x = l4[0]; ll.y = l4[1]; ll.z = l4[2]; ll.w = l4[3];
  ((ushort4*)xh)[(size_t)row * 256 + tid] = hh;
  ((ushort4*)xl)[(size_t)row * 256 + tid] = ll;
}

// ---------------- Wr1 bf16 hi/lo split ---------------------------------------
__global__ __launch_bounds__(256) void split_bf16(const float* __restrict__ src,
                                                  uint16_t* __restrict__ hi,
                                                  uint16_t* __restrict__ lo, long n4) {
  long i = (long)blockIdx.x * 256 + threadIdx.x;
  if (i >= n4) return;
  float4 v = ((const float4*)src)[i];
  float f[4] = {v.x, v.y, v.z, v.w};
  ushort4 hh, ll;
  uint16_t h4[4], l4[4];
#pragma unroll
  for (int j = 0; j < 4; ++j) {
    h4[j] = f2bf(f[j]);
    l4[j] = f2bf(f[j] - bf2f(h4[j]));
  }
  hh.x = h4[0]; hh.y = h4[1]; hh.z = h4[2]; hh.w = h4[3];
  ll.x = l4[0]; ll.y = l4[1]; ll.z = l4[2]; ll.w = l4[3];
  ((ushort4*)hi)[i] = hh;
  ((ushort4*)lo)[i] = ll;
}

// ---------------- y (bf16): per-row absmax-quant -----------------------------
__global__ __launch_bounds__(256) void actquant_y(const uint16_t* __restrict__ Y,
                                                  int8_t* __restrict__ Xq,
                                                  float* __restrict__ rcp_out) {
  const int row = blockIdx.x;
  const int tid = threadIdx.x;
  u16x8 v = ((const u16x8*)(Y + (size_t)row * 2048))[tid];
  float f[8];
  float mx = 0.f;
#pragma unroll
  for (int j = 0; j < 8; ++j) {
    f[j] = bf2f(v[j]);
    mx = fmaxf(mx, fabsf(f[j]));
  }
#pragma unroll
  for (int m = 1; m < 64; m <<= 1) mx = fmaxf(mx, __shfl_xor(mx, m));
  __shared__ float wmax[4];
  const int lane = tid & 63, w = tid >> 6;
  if (lane == 0) wmax[w] = mx;
  __syncthreads();
  mx = fmaxf(fmaxf(wmax[0], wmax[1]), fmaxf(wmax[2], wmax[3]));
  const float M = fmaxf(mx, EPSF);
  const float s = QBF / M;
  uint2 o;
  o.x = pack4(f[0], f[1], f[2], f[3], s);
  o.y = pack4(f[4], f[5], f[6], f[7], s);
  ((uint2*)(Xq + (size_t)row * 2048))[tid] = o;
  if (tid == 0) rcp_out[row] = M / QBF;
}

// ---------------- router GEMM1: bf16x3 split MFMA ----------------------------
__global__ __launch_bounds__(256, 1) void router_mfma(
    const uint16_t* __restrict__ xh, const uint16_t* __restrict__ xl,
    const uint16_t* __restrict__ wh, const uint16_t* __restrict__ wl,
    const float* __restrict__ br1, float* __restrict__ h) {
  __shared__ __align__(16) int8_t smem[2][65536];
  const int tid = threadIdx.x;
  const int lane = tid & 63, wid = tid >> 6;
  const int wm = wid >> 1, wn = wid & 1;
  const int row0 = blockIdx.x * 128, col0 = blockIdx.y * 128;

  const uint16_t* mats[4] = {xh, xl, wh, wl};
  const int rb[4] = {row0, row0, col0, col0};
  const uint8_t* src[16];
#pragma unroll
  for (int R = 0; R < 4; ++R)
#pragma unroll
    for (int i = 0; i < 4; ++i) {
      int p = i * 256 + tid;
      int r = p >> 3, c = p & 7;
      int cs = c ^ (r & 7);
      src[R * 4 + i] = (const uint8_t*)mats[R] + ((long)(rb[R] + r) * IN_D + cs * 8) * 2;
    }

  v4f acc[4][4] = {};
  auto stage = [&](int buf, int kt) {
#pragma unroll
    for (int R = 0; R < 4; ++R)
#pragma unroll
      for (int i = 0; i < 4; ++i)
        load_lds16(src[R * 4 + i] + kt * 128,
                   &smem[buf][R * 16384 + i * 4096 + wid * 1024]);
  };

  stage(0, 0);
  asm volatile("s_waitcnt vmcnt(0)" ::: "memory");
  __syncthreads();
  int buf = 0;
  for (int kt = 0; kt < 16; ++kt) {
    if (kt + 1 < 16) stage(buf ^ 1, kt + 1);
#pragma unroll
    for (int ks = 0; ks < 2; ++ks) {
      v8s ah[4], al[4], bh[4], bl[4];
#pragma unroll
      for (int m = 0; m < 4; ++m) {
        int r = wm * 64 + m * 16 + (lane & 15);
        int ch = (ks * 4 + (lane >> 4)) ^ (r & 7);
        ah[m] = *(const v8s*)&smem[buf][r * 128 + ch * 16];
        al[m] = *(const v8s*)&smem[buf][16384 + r * 128 + ch * 16];
      }
#pragma unroll
      for (int n = 0; n < 4; ++n) {
        int r = wn * 64 + n * 16 + (lane & 15);
        int ch = (ks * 4 + (lane >> 4)) ^ (r & 7);
        bh[n] = *(const v8s*)&smem[buf][32768 + r * 128 + ch * 16];
        bl[n] = *(const v8s*)&smem[buf][49152 + r * 128 + ch * 16];
      }
#pragma unroll
      for (int m = 0; m < 4; ++m)
#pragma unroll
        for (int n = 0; n < 4; ++n) {
          acc[m][n] = __builtin_amdgcn_mfma_f32_16x16x32_bf16(ah[m], bh[n], acc[m][n], 0, 0, 0);
          acc[m][n] = __builtin_amdgcn_mfma_f32_16x16x32_bf16(ah[m], bl[n], acc[m][n], 0, 0, 0);
          acc[m][n] = __builtin_amdgcn_mfma_f32_16x16x32_bf16(al[m], bh[n], acc[m][n], 0, 0, 0);
        }
    }
    asm volatile("s_waitcnt vmcnt(0)" ::: "memory");
    __syncthreads();
    buf ^= 1;
  }

  const int rbase = (lane >> 4) * 4;
  const int cfr = lane & 15;
#pragma unroll
  for (int m = 0; m < 4; ++m)
#pragma unroll
    for (int rg = 0; rg < 4; ++rg) {
      int row = row0 + wm * 64 + m * 16 + rbase + rg;
#pragma unroll
      for (int n = 0; n < 4; ++n) {
        int col = col0 + wn * 64 + n * 16 + cfr;
        h[(long)row * RHD + col] = fmaxf(acc[m][n][rg] + br1[col], 0.f);
      }
    }
}

// ---------------- router stage2 ----------------------------------------------
__global__ __launch_bounds__(256) void router_stage2(const float* __restrict__ h,
                                                     const float* __restrict__ Wr2,
                                                     const float* __restrict__ br2,
                                                     float* __restrict__ probs,
                                                     int* __restrict__ idxg,
                                                     float* __restrict__ gvg,
                                                     int* __restrict__ scount,
                                                     int* __restrict__ suspects) {
  __shared__ float w2s[NEXP * RHD];
  const int tid = threadIdx.x;
  for (int i = tid; i < NEXP * RHD; i += 256) w2s[i] = Wr2[i];
  __syncthreads();
  const int lane = tid & 63, w = tid >> 6;
  const int b = blockIdx.x * 4 + w;
  const float* hrow = h + (long)b * RHD;
  float4 v0 = *(const float4*)&hrow[lane * 8];
  float4 v1 = *(const float4*)&hrow[lane * 8 + 4];
  float hr[8] = {v0.x, v0.y, v0.z, v0.w, v1.x, v1.y, v1.z, v1.w};
  float lg[8];
#pragma unroll
  for (int e = 0; e < 8; ++e) {
    float p = 0.f;
#pragma unroll
    for (int j = 0; j < 8; ++j) p = fmaf(hr[j], w2s[e * RHD + lane * 8 + j], p);
#pragma unroll
    for (int m = 1; m < 64; m <<= 1) p += __shfl_xor(p, m);
    lg[e] = p + br2[e];
  }
  if (lane == 0) {
    float mx = lg[0];
#pragma unroll
    for (int e = 1; e < 8; ++e) mx = fmaxf(mx, lg[e]);
    float ex[8], sum = 0.f;
#pragma unroll
    for (int e = 0; e < 8; ++e) { ex[e] = expf(lg[e] - mx); sum += ex[e]; }
#pragma unroll
    for (int e = 0; e < 8; ++e) probs[(long)b * 8 + e] = ex[e] / sum;
    int i0 = 0; float b0 = lg[0];
#pragma unroll
    for (int e = 1; e < 8; ++e) if (lg[e] > b0) { b0 = lg[e]; i0 = e; }
    int i1 = -1; float b1v = -3.4e38f;
#pragma unroll
    for (int e = 0; e < 8; ++e) if (e != i0 && lg[e] > b1v) { b1v = lg[e]; i1 = e; }
    float b2v = -3.4e38f;
#pragma unroll
    for (int e = 0; e < 8; ++e) if (e != i0 && e != i1 && lg[e] > b2v) b2v = lg[e];
    idxg[b * 2 + 0] = i0; idxg[b * 2 + 1] = i1;
    gvg[b * 2 + 0] = ex[i0] / sum; gvg[b * 2 + 1] = ex[i1] / sum;
    if (b1v - b2v < GAP_DELTA) {
      int p = atomicAdd(scount, 1);
      if (p < B_T) suspects[p] = b;
    }
  }
}

// ---------------- exact fp32 recompute for gap-guard suspects ----------------
__global__ __launch_bounds__(256) void router_fixup(const float* __restrict__ x,
                                                    const float* __restrict__ Wr1,
                                                    const float* __restrict__ br1,
                                                    const float* __restrict__ Wr2,
                                                    const float* __restrict__ br2,
                                                    const int* __restrict__ suspects,
                                                    const int* __restrict__ scount,
                                                    float* __restrict__ probs,
                                                    int* __restrict__ idxg,
                                                    float* __restrict__ gvg) {
  __shared__ float xr[IN_D];
  __shared__ float hr[RHD];
  __shared__ float lgs[NEXP];
  const int n = *scount;
  const int tid = threadIdx.x;
  for (int s = blockIdx.x; s < n && s < B_T; s += 128) {
    const int b = suspects[s];
    __syncthreads();
    for (int i = tid; i < IN_D; i += 256) xr[i] = x[(long)b * IN_D + i];
    __syncthreads();
    {
      const int c0 = tid * 2, c1 = tid * 2 + 1;
      const float* w0 = Wr1 + (long)c0 * IN_D;
      const float* w1 = Wr1 + (long)c1 * IN_D;
      float a0 = 0.f, a1 = 0.f;
      for (int k = 0; k < IN_D; ++k) {
        float xv = xr[k];
        a0 = fmaf(xv, w0[k], a0);
        a1 = fmaf(xv, w1[k], a1);
      }
      hr[c0] = fmaxf(a0 + br1[c0], 0.f);
      hr[c1] = fmaxf(a1 + br1[c1], 0.f);
    }
    __syncthreads();
    if (tid < NEXP) {
      const float* w2 = Wr2 + (long)tid * RHD;
      float a = 0.f;
      for (int k = 0; k < RHD; ++k) a = fmaf(hr[k], w2[k], a);
      lgs[tid] = a + br2[tid];
    }
    __syncthreads();
    if (tid == 0) {
      float lg[8];
#pragma unroll
      for (int e = 0; e < 8; ++e) lg[e] = lgs[e];
      float mx = lg[0];
#pragma unroll
      for (int e = 1; e < 8; ++e) mx = fmaxf(mx, lg[e]);
      float ex[8], sum = 0.f;
#pragma unroll
      for (int e = 0; e < 8; ++e) { ex[e] = expf(lg[e] - mx); sum += ex[e]; }
#pragma unroll
      for (int e = 0; e < 8; ++e) probs[(long)b * 8 + e] = ex[e] / sum;
      int i0 = 0; float b0 = lg[0];
#pragma unroll
      for (int e = 1; e < 8; ++e) if (lg[e] > b0) { b0 = lg[e]; i0 = e; }
      int i1 = -1; float b1v = -3.4e38f;
#pragma unroll
      for (int e = 0; e < 8; ++e) if (e != i0 && lg[e] > b1v) { b1v = lg[e]; i1 = e; }
      idxg[b * 2 + 0] = i0; idxg[b * 2 + 1] = i1;
      gvg[b * 2 + 0] = ex[i0] / sum; gvg[b * 2 + 1] = ex[i1] / sum;
    }
  }
}

// ---------------- histogram / scan / placement -------------------------------
__global__ __launch_bounds__(256) void hist_block(const int* __restrict__ idxg,
                                                  int* __restrict__ bc) {
  __shared__ int hloc[NEXP];
  const int t = threadIdx.x;
  if (t < NEXP) hloc[t] = 0;
  __syncthreads();
  int a = blockIdx.x * 256 + t;
  atomicAdd(&hloc[idxg[a]], 1);
  __syncthreads();
  if (t < NEXP) bc[blockIdx.x * NEXP + t] = hloc[t];
}

__global__ void scan_all(const int* __restrict__ bc, int* __restrict__ blockbase,
                         int* __restrict__ ntiles, int* __restrict__ te,
                         int* __restrict__ ts, int* __restrict__ tc,
                         float* __restrict__ loss_out) {
  __shared__ int counts[NEXP], basep[NEXP];
  const int t = threadIdx.x;
  if (t < NEXP) {
    int s = 0;
    for (int b = 0; b < 64; ++b) s += bc[b * NEXP + t];
    counts[t] = s;
  }
  __syncthreads();
  if (t == 0) {
    int acc = 0, nb = 0;
    for (int e = 0; e < NEXP; ++e) {
      basep[e] = acc;
      int c = counts[e];
      int nt = (c + 255) >> 8;
      for (int i = 0; i < nt; ++i) {
        te[nb] = e; ts[nb] = acc + i * 256; tc[nb] = min(256, c - i * 256); ++nb;
      }
      acc += c;
    }
    *ntiles = nb;
    *loss_out = 0.f;
  }
  __syncthreads();
  if (t < NEXP) {
    int run = basep[t];
    for (int b = 0; b < 64; ++b) { blockbase[b * NEXP + t] = run; run += bc[b * NEXP + t]; }
  }
}

__global__ __launch_bounds__(256) void place2(const int* __restrict__ idxg,
                                              const int* __restrict__ blockbase,
                                              int* __restrict__ token_list,
                                              int* __restrict__ slotmap) {
  __shared__ int cur[NEXP];
  const int t = threadIdx.x;
  if (t < NEXP) cur[t] = blockbase[blockIdx.x * NEXP + t];
  __syncthreads();
  int a = blockIdx.x * 256 + t;
  int e = idxg[a];
  int pos = atomicAdd(&cur[e], 1);
  token_list[pos] = a >> 1;
  slotmap[a] = pos;
}

// ---------------- int8 ternary MFMA GEMM -------------------------------------
// 256x256 tile, BK=64 bytes, 8 waves, 64KB LDS (2 K-tile dbuf) -> 2 blocks/CU.
// 4 quadrant phases per K-tile; each phase stages ONE half of next K-tile
// (order B1,A0,B0,A1); counted waits vmcnt(1)@q0, vmcnt(2)@q2 (0 on last tile).
// LDS per buf: A0 8KB | A1 8KB | B0 8KB | B1 8KB.
template <int KDIM, bool INDIRECT, bool RELU, bool FINAL>
__global__ __launch_bounds__(512, 4) void gemm_i8(
    const int8_t* __restrict__ Aq, const int8_t* __restrict__ Wq,
    const float* __restrict__ swf_layer, const float* __restrict__ rcp_act,
    const float* __restrict__ bias, const int* __restrict__ te,
    const int* __restrict__ ts, const int* __restrict__ tc,
    const int* __restrict__ ntiles_p, const int* __restrict__ token_list,
    void* __restrict__ Yout, int Nvalid) {
  if ((int)blockIdx.y >= *ntiles_p) return;
  extern __shared__ __align__(16) int8_t smem_dyn[];  // 2 x 32KB
  const int t = blockIdx.y;
  const int e = te[t], row0 = ts[t], rcount = tc[t];
  const int col0 = blockIdx.x * 256;
  const int tid = threadIdx.x;
  const int lane = tid & 63, wid = tid >> 6;
  const int wsm = wid >> 2, wsn = wid & 3;
  const int fr = lane & 15, hi = lane >> 4;

  // staging source ptrs: half hh, position tid -> row r=tid>>2, chunk c=tid&3
  // pre-swizzled source chunk: cs = c ^ ((r>>1)&3); one load per thread per half
  const int8_t* sA[2];
  const int8_t* sB[2];
  {
    int r = tid >> 2, c = tid & 3;
    int cs = c ^ ((r >> 1) & 3);
#pragma unroll
    for (int hh = 0; hh < 2; ++hh) {
      int rt = hh * 128 + r;
      int ar = row0 + min(rt, rcount - 1);
      long arow = INDIRECT ? (long)token_list[ar] : (long)ar;
      sA[hh] = Aq + arow * KDIM + cs * 16;
      int br = min(col0 + rt, Nvalid - 1);
      sB[hh] = Wq + ((long)e * Nvalid + br) * (long)KDIM + cs * 16;
    }
  }

  // which: 0=A0, 1=A1, 2=B0, 3=B1 ; region offset = (which&1)*8192 + (which>>1)*16384
  auto stage = [&](int buf, int kt, int which) {
    const int hh = which & 1;
    const int8_t* p = (which >= 2) ? sB[hh] : sA[hh];
    int dst = buf * 32768 + (which & 1) * 8192 + ((which >> 1) & 1) * 16384 + wid * 1024;
    load_lds16(p + (long)kt * 64, &smem_dyn[dst]);
  };

  // per-lane constant ds_read swizzle: cs = hi ^ ((fr>>1)&3)
  const int swzc = (hi ^ ((fr >> 1) & 3)) * 16 + fr * 64;

  v4i acc[2][2][4][2] = {};  // [qm][qn][mi][ni]
  v4i aF[4];
  v4i bF[2][2];

  constexpr int KT = KDIM / 64;
  // prologue: stage tile0's 4 halves in steady order B1,A0,B0,A1 (buf0)
  stage(0, 0, 3); stage(0, 0, 0); stage(0, 0, 2); stage(0, 0, 1);

  for (int kt = 0; kt < KT; ++kt) {
    const int buf = kt & 1;
    const int base = buf * 32768;
    // ===== q0: (A0,B0); stage B1(t+1)
    asm volatile("s_waitcnt vmcnt(1)" ::: "memory");
    asm volatile("s_barrier" ::: "memory");
#pragma unroll
    for (int mi = 0; mi < 4; ++mi)
      aF[mi] = *(const v4i*)&smem_dyn[base + (wsm * 64 + mi * 16) * 64 + swzc];
#pragma unroll
    for (int ni = 0; ni < 2; ++ni)
      bF[0][ni] = *(const v4i*)&smem_dyn[base + 16384 + (wsn * 32 + ni * 16) * 64 + swzc];
    if (kt + 1 < KT) stage(buf ^ 1, kt + 1, 3);
    __builtin_amdgcn_s_setprio(1);
#pragma unroll
    for (int mi = 0; mi < 4; ++mi)
#pragma unroll
      for (int ni = 0; ni < 2; ++ni)
        acc[0][0][mi][ni] = __builtin_amdgcn_mfma_i32_16x16x64_i8(aF[mi], bF[0][ni], acc[0][0][mi][ni], 0, 0, 0);
    __builtin_amdgcn_s_setprio(0);
    // ===== q1: (A0,B1); stage A0(t+1)
    asm volatile("s_barrier" ::: "memory");
#pragma unroll
    for (int ni = 0; ni < 2; ++ni)
      bF[1][ni] = *(const v4i*)&smem_dyn[base + 24576 + (wsn * 32 + ni * 16) * 64 + swzc];
    if (kt + 1 < KT) stage(buf ^ 1, kt + 1, 0);
    __builtin_amdgcn_s_setprio(1);
#pragma unroll
    for (int mi = 0; mi < 4; ++mi)
#pragma unroll
      for (int ni = 0; ni < 2; ++ni)
        acc[0][1][mi][ni] = __builtin_amdgcn_mfma_i32_16x16x64_i8(aF[mi], bF[1][ni], acc[0][1][mi][ni], 0, 0, 0);
    __builtin_amdgcn_s_setprio(0);
    // ===== q2: (A1,B0); stage B0(t+1); wait for A1(t)
    if (kt + 1 < KT) {
      asm volatile("s_waitcnt vmcnt(2)" ::: "memory");
    } else {
      asm volatile("s_waitcnt vmcnt(0)" ::: "memory");
    }
    asm volatile("s_barrier" ::: "memory");
#pragma unroll
    for (int mi = 0; mi < 4; ++mi)
      aF[mi] = *(const v4i*)&smem_dyn[base + 8192 + (wsm * 64 + mi * 16) * 64 + swzc];
    if (kt + 1 < KT) stage(buf ^ 1, kt + 1, 2);
    __builtin_amdgcn_s_setprio(1);
#pragma unroll
    for (int mi = 0; mi < 4; ++mi)
#pragma unroll
      for (int ni = 0; ni < 2; ++ni)
        acc[1][0][mi][ni] = __builtin_amdgcn_mfma_i32_16x16x64_i8(aF[mi], bF[0][ni], acc[1][0][mi][ni], 0, 0, 0);
    __builtin_amdgcn_s_setprio(0);
    // ===== q3: (A1,B1); stage A1(t+1); no new reads
    asm volatile("s_barrier" ::: "memory");
    if (kt + 1 < KT) stage(buf ^ 1, kt + 1, 1);
    __builtin_amdgcn_s_setprio(1);
#pragma unroll
    for (int mi = 0; mi < 4; ++mi)
#pragma unroll
      for (int ni = 0; ni < 2; ++ni)
        acc[1][1][mi][ni] = __builtin_amdgcn_mfma_i32_16x16x64_i8(aF[mi], bF[1][ni], acc[1][1][mi][ni], 0, 0, 0);
    __builtin_amdgcn_s_setprio(0);
  }

  // ---- epilogue
  const float sw = swf_layer[e];
  const int rbase = hi * 4;
  const float* bias_e = bias + (long)e * Nvalid;
#pragma unroll
  for (int qm = 0; qm < 2; ++qm)
#pragma unroll
    for (int mi = 0; mi < 4; ++mi)
#pragma unroll
      for (int rg = 0; rg < 4; ++rg) {
        int trow = qm * 128 + wsm * 64 + mi * 16 + rbase + rg;
        if (trow >= rcount) continue;
        int slot = row0 + trow;
        float rcp = rcp_act[INDIRECT ? token_list[slot] : slot];
        float dq = sw * rcp;
        if constexpr (!FINAL) {
          uint16_t* yrow = (uint16_t*)Yout + (long)slot * 2048;
#pragma unroll
          for (int qn = 0; qn < 2; ++qn)
#pragma unroll
            for (int ni = 0; ni < 2; ++ni) {
              int o = col0 + qn * 128 + wsn * 32 + ni * 16 + fr;
              float v = (float)acc[qm][qn][mi][ni][rg] * dq + bias_e[o];
              if (RELU) v = fmaxf(v, 0.f);
              yrow[o] = f2bf(v);
            }
        } else {
          float* zrow = (float*)Yout + (long)slot * 1024;
#pragma unroll
          for (int qn = 0; qn < 2; ++qn)
#pragma unroll
            for (int ni = 0; ni < 2; ++ni) {
              int o = col0 + qn * 128 + wsn * 32 + ni * 16 + fr;
              float bb2 = bias_e[min(o, Nvalid - 1)];
              zrow[o] = (float)acc[qm][qn][mi][ni][rg] * dq + bb2;
            }
        }
      }
}

// ---------------- gate-weighted combine --------------------------------------
__global__ __launch_bounds__(256) void combine(const float* __restrict__ z,
                                               const int* __restrict__ slotmap,
                                               const float* __restrict__ gvg,
                                               float* __restrict__ out) {
  const int b = blockIdx.x;
  const int c = threadIdx.x;
  if (c >= 250) return;
  const int s0 = slotmap[b * 2], s1 = slotmap[b * 2 + 1];
  const float g0 = gvg[b * 2] * 0.5f, g1 = gvg[b * 2 + 1] * 0.5f;
  float4 a = *(const float4*)(z + (long)s0 * 1024 + c * 4);
  float4 q = *(const float4*)(z + (long)s1 * 1024 + c * 4);
  float4 o = {g0 * a.x + g1 * q.x, g0 * a.y + g1 * q.y,
              g0 * a.z + g1 * q.z, g0 * a.w + g1 * q.w};
  *(float4*)(out + (long)b * CDIM + c * 4) = o;
}

// ---------------- host launcher ----------------------------------------------
extern "C" void kernel_launch(void* const* d_in, const int* in_sizes, int n_in,
                              void* d_out, int out_size, void* d_ws, size_t ws_size,
                              hipStream_t stream) {
  const float* x   = (const float*)d_in[0];
  const float* Wr1 = (const float*)d_in[1];
  const float* br1 = (const float*)d_in[2];
  const float* Wr2 = (const float*)d_in[3];
  const float* br2 = (const float*)d_in[4];
  const float* W1  = (const float*)d_in[5];
  const float* b1  = (const float*)d_in[6];
  const float* W2  = (const float*)d_in[7];
  const float* b2  = (const float*)d_in[8];
  const float* W3  = (const float*)d_in[9];
  const float* b3  = (const float*)d_in[10];
  float* out = (float*)d_out;
  char* ws = (char*)d_ws;

  size_t off = 0;
  auto alloc = [&](size_t sz) { size_t r = off; off = (off + sz + 255) & ~(size_t)255; return r; };
  size_t O_META  = alloc(8192);
  size_t O_SUSP  = alloc(B_T * sizeof(int));
  size_t O_PART  = alloc(24 * 64 * sizeof(double));
  size_t O_SWF   = alloc(24 * sizeof(float));
  size_t O_RCPX  = alloc(B_T * sizeof(float));
  size_t O_IDX   = alloc(B_T * 2 * sizeof(int));
  size_t O_GVG   = alloc(B_T * 2 * sizeof(float));
  size_t O_TLIST = alloc(NSLOT * sizeof(int));
  size_t O_SLOT  = alloc(B_T * 2 * sizeof(int));
  size_t O_S1    = alloc(NSLOT * sizeof(float));
  size_t O_S2    = alloc(NSLOT * sizeof(float));
  size_t O_XQ    = alloc((size_t)B_T * IN_D);
  size_t O_WQ1   = alloc((size_t)NEXP * H1D * IN_D);
  size_t O_WQ2   = alloc((size_t)NEXP * H2D * H1D);
  size_t O_WQ3   = alloc((size_t)NEXP * CDIM * H2D);
  size_t O_YQ    = alloc((size_t)NSLOT * 2048);
  size_t O_YBIG  = alloc((size_t)NSLOT * 2048 * sizeof(float));
  (void)ws_size; (void)in_sizes; (void)n_in;

  int*    te     = (int*)(ws + O_META);
  int*    tsv    = te + 144;
  int*    tcv    = tsv + 144;
  int*    ntiles = tcv + 144;
  int*    bc     = ntiles + 4;
  int*    bbase  = bc + 512;
  int*    scount = bbase + 512;
  int*    susp   = (int*)(ws + O_SUSP);
  double* part   = (double*)(ws + O_PART);
  float*  swf    = (float*)(ws + O_SWF);
  float*  rcpx   = (float*)(ws + O_RCPX);
  int*    idxg   = (int*)(ws + O_IDX);
  float*  gvg    = (float*)(ws + O_GVG);
  int*    tlist  = (int*)(ws + O_TLIST);
  int*    slotmap= (int*)(ws + O_SLOT);
  float*  s1     = (float*)(ws + O_S1);
  float*  s2     = (float*)(ws + O_S2);
  int8_t* Xq     = (int8_t*)(ws + O_XQ);
  int8_t* wq1    = (int8_t*)(ws + O_WQ1);
  int8_t* wq2    = (int8_t*)(ws + O_WQ2);
  int8_t* wq3    = (int8_t*)(ws + O_WQ3);
  float*  Ybig   = (float*)(ws + O_YBIG);   // router h (fp32); y (bf16); z (fp32)
  float*  h      = Ybig;
  uint16_t* ybf  = (uint16_t*)Ybig;
  float*  zbuf   = Ybig;
  int8_t* Yq     = (int8_t*)(ws + O_YQ);

  char* ybytes = (char*)Ybig;
  uint16_t* xh = (uint16_t*)(ybytes + (80l << 20));
  uint16_t* xl = (uint16_t*)(ybytes + (97l << 20));
  uint16_t* wh = (uint16_t*)(ybytes + (114l << 20));
  uint16_t* wl = (uint16_t*)(ybytes + (116l << 20));

  hipMemsetAsync(ws + O_META, 0, 8192, stream);

  // weight scales + ternary quant (ILP-4)
  wabs_all<<<dim3(64, 24), 256, 0, stream>>>(W1, W2, W3, part);
  finalize_scales<<<1, 64, 0, stream>>>(part, swf);
  wquant_all<<<dim3(64, 24), 256, 0, stream>>>(W1, W2, W3, wq1, wq2, wq3, swf);

  // x: fused quant + split; Wr1 split
  actquant_split<<<B_T, 256, 0, stream>>>(x, Xq, rcpx, xh, xl);
  split_bf16<<<512, 256, 0, stream>>>(Wr1, wh, wl, (long)RHD * IN_D / 4);

  // router
  router_mfma<<<dim3(B_T / 128, RHD / 128), 256, 0, stream>>>(xh, xl, wh, wl, br1, h);
  router_stage2<<<B_T / 4, 256, 0, stream>>>(h, Wr2, br2, out + (size_t)B_T * CDIM,
                                             idxg, gvg, scount, susp);
  router_fixup<<<128, 256, 0, stream>>>(x, Wr1, br1, Wr2, br2, susp, scount,
                                        out + (size_t)B_T * CDIM, idxg, gvg);
  hist_block<<<64, 256, 0, stream>>>(idxg, bc);
  scan_all<<<1, 64, 0, stream>>>(bc, bbase, ntiles, te, tsv, tcv,
                                 out + (size_t)B_T * CDIM + (size_t)B_T * NEXP);
  place2<<<64, 256, 0, stream>>>(idxg, bbase, tlist, slotmap);

  // expert layers (int8 MFMA; BK=64, 64KB LDS -> 2 blocks/CU; y bf16)
  gemm_i8<IN_D, true, true, false><<<dim3(H1D / 256, MAXT), 512, 65536, stream>>>(
      Xq, wq1, swf + 0, rcpx, b1, te, tsv, tcv, ntiles, tlist, (void*)ybf, H1D);
  actquant_y<<<NSLOT, 256, 0, stream>>>(ybf, Yq, s1);
  gemm_i8<2048, false, true, false><<<dim3(H2D / 256, MAXT), 512, 65536, stream>>>(
      Yq, wq2, swf + 8, s1, b2, te, tsv, tcv, ntiles, tlist, (void*)ybf, H2D);
  actquant_y<<<NSLOT, 256, 0, stream>>>(ybf, Yq, s2);
  gemm_i8<2048, false, false, true><<<dim3(1024 / 256, MAXT), 512, 65536, stream>>>(
      Yq, wq3, swf + 16, s2, b3, te, tsv, tcv, ntiles, tlist, (void*)zbuf, CDIM);

  // gate-weighted combine into d_out
  combine<<<B_T, 256, 0, stream>>>(zbuf, slotmap, gvg, out);
}

// Round 12
// 564.470 us; speedup vs baseline: 3.1851x; 3.1851x over previous
//
#include <hip/hip_runtime.h>
#include <stdint.h>

#define DEV static __device__ __forceinline__

typedef int v4i __attribute__((ext_vector_type(4)));
typedef short v8s __attribute__((ext_vector_type(8)));
typedef float v4f __attribute__((ext_vector_type(4)));
typedef unsigned short u16x8 __attribute__((ext_vector_type(8)));

constexpr int B_T   = 8192;
constexpr int IN_D  = 1024;
constexpr int H1D   = 2048;
constexpr int H2D   = 2048;
constexpr int CDIM  = 1000;
constexpr int NEXP  = 8;
constexpr int RHD   = 512;
constexpr float QBF  = 127.0f;
constexpr float EPSF = 1e-5f;
constexpr int NSLOT = 2 * B_T;
constexpr int MAXT  = 72;
constexpr float GAP_DELTA = 2e-3f;

DEV void load_lds16(const void* g, void* l) {
  __builtin_amdgcn_global_load_lds(
      (const __attribute__((address_space(1))) uint32_t*)(uintptr_t)g,
      (__attribute__((address_space(3))) uint32_t*)(uint32_t)(uintptr_t)l,
      16, 0, 0);
}

DEV uint32_t pack4(float a, float b, float c, float d, float s) {
  int q0 = (int)rintf(a * s); q0 = q0 > 127 ? 127 : (q0 < -127 ? -127 : q0);
  int q1 = (int)rintf(b * s); q1 = q1 > 127 ? 127 : (q1 < -127 ? -127 : q1);
  int q2 = (int)rintf(c * s); q2 = q2 > 127 ? 127 : (q2 < -127 ? -127 : q2);
  int q3 = (int)rintf(d * s); q3 = q3 > 127 ? 127 : (q3 < -127 ? -127 : q3);
  return (uint32_t)(uint8_t)q0 | ((uint32_t)(uint8_t)q1 << 8) |
         ((uint32_t)(uint8_t)q2 << 16) | ((uint32_t)(uint8_t)q3 << 24);
}

DEV uint16_t f2bf(float f) {
  uint32_t u = __float_as_uint(f);
  return (uint16_t)((u + 0x7FFFu + ((u >> 16) & 1u)) >> 16);
}
DEV float bf2f(uint16_t h) { return __uint_as_float((uint32_t)h << 16); }

// ---- slice helper: t in [0,24) -> tensor/expert slice -----------------------
DEV const float* slice_base(int t, const float* W1, const float* W2, const float* W3,
                            long& n4) {
  const float* W; long perExpert;
  if (t < 8)       { W = W1; perExpert = (long)H1D * IN_D; }
  else if (t < 16) { W = W2; perExpert = (long)H2D * H1D; }
  else             { W = W3; perExpert = (long)CDIM * H2D; }
  n4 = perExpert >> 2;
  return W + (long)(t & 7) * perExpert;
}

// ---------------- weight |.| mean reduction (ILP-4, one launch) --------------
__global__ __launch_bounds__(256) void wabs_all(const float* __restrict__ W1,
                                                const float* __restrict__ W2,
                                                const float* __restrict__ W3,
                                                double* __restrict__ partial) {
  const int t = blockIdx.y;
  long n4;
  const float4* base = (const float4*)slice_base(t, W1, W2, W3, n4);
  double s0 = 0.0, s1 = 0.0, s2 = 0.0, s3 = 0.0;
  const long stride4 = 64L * 256L * 4L;
  for (long i4 = ((long)blockIdx.x * 256 + threadIdx.x) * 4; i4 < n4; i4 += stride4) {
    float4 a = base[i4 + 0];
    float4 b = base[i4 + 1];
    float4 c = base[i4 + 2];
    float4 d = base[i4 + 3];
    s0 += (double)fabsf(a.x) + (double)fabsf(a.y) + (double)fabsf(a.z) + (double)fabsf(a.w);
    s1 += (double)fabsf(b.x) + (double)fabsf(b.y) + (double)fabsf(b.z) + (double)fabsf(b.w);
    s2 += (double)fabsf(c.x) + (double)fabsf(c.y) + (double)fabsf(c.z) + (double)fabsf(c.w);
    s3 += (double)fabsf(d.x) + (double)fabsf(d.y) + (double)fabsf(d.z) + (double)fabsf(d.w);
  }
  __shared__ double red[256];
  red[threadIdx.x] = (s0 + s1) + (s2 + s3);
  __syncthreads();
  for (int st = 128; st > 0; st >>= 1) {
    if ((int)threadIdx.x < st) red[threadIdx.x] += red[threadIdx.x + st];
    __syncthreads();
  }
  if (threadIdx.x == 0) partial[(long)t * 64 + blockIdx.x] = red[0];
}

__global__ void finalize_scales(const double* __restrict__ partial, float* __restrict__ swf) {
  int t = threadIdx.x;
  if (t >= 24) return;
  double s = 0.0;
  for (int i = 0; i < 64; ++i) s += partial[t * 64 + i];
  long cnt = (t < 8) ? (long)H1D * IN_D : (t < 16) ? (long)H2D * H1D : (long)CDIM * H2D;
  float mean = (float)(s / (double)cnt);
  swf[t] = fmaxf(mean, EPSF);
}

// ---------------- ternary weight quantization (all slices, ILP-4) ------------
__global__ __launch_bounds__(256) void wquant_all(const float* __restrict__ W1,
                                                  const float* __restrict__ W2,
                                                  const float* __restrict__ W3,
                                                  int8_t* __restrict__ wq1,
                                                  int8_t* __restrict__ wq2,
                                                  int8_t* __restrict__ wq3,
                                                  const float* __restrict__ swf) {
  const int t = blockIdx.y;
  long n4;
  const float4* base = (const float4*)slice_base(t, W1, W2, W3, n4);
  int8_t* Wq = (t < 8) ? wq1 : (t < 16) ? wq2 : wq3;
  uint32_t* out = (uint32_t*)(Wq) + (long)(t & 7) * n4;
  const float s = swf[t];
  const long stride4 = 64L * 256L * 4L;
  for (long i4 = ((long)blockIdx.x * 256 + threadIdx.x) * 4; i4 < n4; i4 += stride4) {
#pragma unroll
    for (int j = 0; j < 4; ++j) {
      float4 v = base[i4 + j];
      float t0 = fminf(fmaxf(rintf(v.x / s), -1.f), 1.f);
      float t1 = fminf(fmaxf(rintf(v.y / s), -1.f), 1.f);
      float t2 = fminf(fmaxf(rintf(v.z / s), -1.f), 1.f);
      float t3 = fminf(fmaxf(rintf(v.w / s), -1.f), 1.f);
      out[i4 + j] = (uint32_t)(uint8_t)(int8_t)t0 | ((uint32_t)(uint8_t)(int8_t)t1 << 8) |
                    ((uint32_t)(uint8_t)(int8_t)t2 << 16) | ((uint32_t)(uint8_t)(int8_t)t3 << 24);
    }
  }
}

// ---------------- x: fused absmax-quant + bf16 hi/lo split -------------------
__global__ __launch_bounds__(256) void actquant_split(const float* __restrict__ X,
                                                      int8_t* __restrict__ Xq,
                                                      float* __restrict__ rcp_out,
                                                      uint16_t* __restrict__ xh,
                                                      uint16_t* __restrict__ xl) {
  const int row = blockIdx.x;
  const int tid = threadIdx.x;
  float4 v = ((const float4*)(X + (size_t)row * IN_D))[tid];
  float mx = fmaxf(fmaxf(fabsf(v.x), fabsf(v.y)), fmaxf(fabsf(v.z), fabsf(v.w)));
#pragma unroll
  for (int m = 1; m < 64; m <<= 1) mx = fmaxf(mx, __shfl_xor(mx, m));
  __shared__ float wmax[4];
  const int lane = tid & 63, w = tid >> 6;
  if (lane == 0) wmax[w] = mx;
  __syncthreads();
  mx = fmaxf(fmaxf(wmax[0], wmax[1]), fmaxf(wmax[2], wmax[3]));
  const float M = fmaxf(mx, EPSF);
  const float s = QBF / M;
  ((uint32_t*)(Xq + (size_t)row * IN_D))[tid] = pack4(v.x, v.y, v.z, v.w, s);
  if (tid == 0) rcp_out[row] = M / QBF;
  float f[4] = {v.x, v.y, v.z, v.w};
  ushort4 hh, ll;
  uint16_t h4[4], l4[4];
#pragma unroll
  for (int j = 0; j < 4; ++j) {
    h4[j] = f2bf(f[j]);
    l4[j] = f2bf(f[j] - bf2f(h4[j]));
  }
  hh.x = h4[0]; hh.y = h4[1]; hh.z = h4[2]; hh.w = h4[3];
  ll.x = l4[0]; ll.y = l4[1]; ll.z = l4[2]; ll.w = l4[3];
  ((ushort4*)xh)[(size_t)row * 256 + tid] = hh;
  ((ushort4*)xl)[(size_t)row * 256 + tid] = ll;
}

// ---------------- Wr1 bf16 hi/lo split ---------------------------------------
__global__ __launch_bounds__(256) void split_bf16(const float* __restrict__ src,
                                                  uint16_t* __restrict__ hi,
                                                  uint16_t* __restrict__ lo, long n4) {
  long i = (long)blockIdx.x * 256 + threadIdx.x;
  if (i >= n4) return;
  float4 v = ((const float4*)src)[i];
  float f[4] = {v.x, v.y, v.z, v.w};
  ushort4 hh, ll;
  uint16_t h4[4], l4[4];
#pragma unroll
  for (int j = 0; j < 4; ++j) {
    h4[j] = f2bf(f[j]);
    l4[j] = f2bf(f[j] - bf2f(h4[j]));
  }
  hh.x = h4[0]; hh.y = h4[1]; hh.z = h4[2]; hh.w = h4[3];
  ll.x = l4[0]; ll.y = l4[1]; ll.z = l4[2]; ll.w = l4[3];
  ((ushort4*)hi)[i] = hh;
  ((ushort4*)lo)[i] = ll;
}

// ---------------- y (bf16): per-row absmax-quant -----------------------------
__global__ __launch_bounds__(256) void actquant_y(const uint16_t* __restrict__ Y,
                                                  int8_t* __restrict__ Xq,
                                                  float* __restrict__ rcp_out) {
  const int row = blockIdx.x;
  const int tid = threadIdx.x;
  u16x8 v = ((const u16x8*)(Y + (size_t)row * 2048))[tid];
  float f[8];
  float mx = 0.f;
#pragma unroll
  for (int j = 0; j < 8; ++j) {
    f[j] = bf2f(v[j]);
    mx = fmaxf(mx, fabsf(f[j]));
  }
#pragma unroll
  for (int m = 1; m < 64; m <<= 1) mx = fmaxf(mx, __shfl_xor(mx, m));
  __shared__ float wmax[4];
  const int lane = tid & 63, w = tid >> 6;
  if (lane == 0) wmax[w] = mx;
  __syncthreads();
  mx = fmaxf(fmaxf(wmax[0], wmax[1]), fmaxf(wmax[2], wmax[3]));
  const float M = fmaxf(mx, EPSF);
  const float s = QBF / M;
  uint2 o;
  o.x = pack4(f[0], f[1], f[2], f[3], s);
  o.y = pack4(f[4], f[5], f[6], f[7], s);
  ((uint2*)(Xq + (size_t)row * 2048))[tid] = o;
  if (tid == 0) rcp_out[row] = M / QBF;
}

// ---------------- router GEMM1: bf16x3 split MFMA ----------------------------
__global__ __launch_bounds__(256, 1) void router_mfma(
    const uint16_t* __restrict__ xh, const uint16_t* __restrict__ xl,
    const uint16_t* __restrict__ wh, const uint16_t* __restrict__ wl,
    const float* __restrict__ br1, float* __restrict__ h) {
  __shared__ __align__(16) int8_t smem[2][65536];
  const int tid = threadIdx.x;
  const int lane = tid & 63, wid = tid >> 6;
  const int wm = wid >> 1, wn = wid & 1;
  const int row0 = blockIdx.x * 128, col0 = blockIdx.y * 128;

  const uint16_t* mats[4] = {xh, xl, wh, wl};
  const int rb[4] = {row0, row0, col0, col0};
  const uint8_t* src[16];
#pragma unroll
  for (int R = 0; R < 4; ++R)
#pragma unroll
    for (int i = 0; i < 4; ++i) {
      int p = i * 256 + tid;
      int r = p >> 3, c = p & 7;
      int cs = c ^ (r & 7);
      src[R * 4 + i] = (const uint8_t*)mats[R] + ((long)(rb[R] + r) * IN_D + cs * 8) * 2;
    }

  v4f acc[4][4] = {};
  auto stage = [&](int buf, int kt) {
#pragma unroll
    for (int R = 0; R < 4; ++R)
#pragma unroll
      for (int i = 0; i < 4; ++i)
        load_lds16(src[R * 4 + i] + kt * 128,
                   &smem[buf][R * 16384 + i * 4096 + wid * 1024]);
  };

  stage(0, 0);
  asm volatile("s_waitcnt vmcnt(0)" ::: "memory");
  __syncthreads();
  int buf = 0;
  for (int kt = 0; kt < 16; ++kt) {
    if (kt + 1 < 16) stage(buf ^ 1, kt + 1);
#pragma unroll
    for (int ks = 0; ks < 2; ++ks) {
      v8s ah[4], al[4], bh[4], bl[4];
#pragma unroll
      for (int m = 0; m < 4; ++m) {
        int r = wm * 64 + m * 16 + (lane & 15);
        int ch = (ks * 4 + (lane >> 4)) ^ (r & 7);
        ah[m] = *(const v8s*)&smem[buf][r * 128 + ch * 16];
        al[m] = *(const v8s*)&smem[buf][16384 + r * 128 + ch * 16];
      }
#pragma unroll
      for (int n = 0; n < 4; ++n) {
        int r = wn * 64 + n * 16 + (lane & 15);
        int ch = (ks * 4 + (lane >> 4)) ^ (r & 7);
        bh[n] = *(const v8s*)&smem[buf][32768 + r * 128 + ch * 16];
        bl[n] = *(const v8s*)&smem[buf][49152 + r * 128 + ch * 16];
      }
#pragma unroll
      for (int m = 0; m < 4; ++m)
#pragma unroll
        for (int n = 0; n < 4; ++n) {
          acc[m][n] = __builtin_amdgcn_mfma_f32_16x16x32_bf16(ah[m], bh[n], acc[m][n], 0, 0, 0);
          acc[m][n] = __builtin_amdgcn_mfma_f32_16x16x32_bf16(ah[m], bl[n], acc[m][n], 0, 0, 0);
          acc[m][n] = __builtin_amdgcn_mfma_f32_16x16x32_bf16(al[m], bh[n], acc[m][n], 0, 0, 0);
        }
    }
    asm volatile("s_waitcnt vmcnt(0)" ::: "memory");
    __syncthreads();
    buf ^= 1;
  }

  const int rbase = (lane >> 4) * 4;
  const int cfr = lane & 15;
#pragma unroll
  for (int m = 0; m < 4; ++m)
#pragma unroll
    for (int rg = 0; rg < 4; ++rg) {
      int row = row0 + wm * 64 + m * 16 + rbase + rg;
#pragma unroll
      for (int n = 0; n < 4; ++n) {
        int col = col0 + wn * 64 + n * 16 + cfr;
        h[(long)row * RHD + col] = fmaxf(acc[m][n][rg] + br1[col], 0.f);
      }
    }
}

// ---------------- router stage2 ----------------------------------------------
__global__ __launch_bounds__(256) void router_stage2(const float* __restrict__ h,
                                                     const float* __restrict__ Wr2,
                                                     const float* __restrict__ br2,
                                                     float* __restrict__ probs,
                                                     int* __restrict__ idxg,
                                                     float* __restrict__ gvg,
                                                     int* __restrict__ scount,
                                                     int* __restrict__ suspects) {
  __shared__ float w2s[NEXP * RHD];
  const int tid = threadIdx.x;
  for (int i = tid; i < NEXP * RHD; i += 256) w2s[i] = Wr2[i];
  __syncthreads();
  const int lane = tid & 63, w = tid >> 6;
  const int b = blockIdx.x * 4 + w;
  const float* hrow = h + (long)b * RHD;
  float4 v0 = *(const float4*)&hrow[lane * 8];
  float4 v1 = *(const float4*)&hrow[lane * 8 + 4];
  float hr[8] = {v0.x, v0.y, v0.z, v0.w, v1.x, v1.y, v1.z, v1.w};
  float lg[8];
#pragma unroll
  for (int e = 0; e < 8; ++e) {
    float p = 0.f;
#pragma unroll
    for (int j = 0; j < 8; ++j) p = fmaf(hr[j], w2s[e * RHD + lane * 8 + j], p);
#pragma unroll
    for (int m = 1; m < 64; m <<= 1) p += __shfl_xor(p, m);
    lg[e] = p + br2[e];
  }
  if (lane == 0) {
    float mx = lg[0];
#pragma unroll
    for (int e = 1; e < 8; ++e) mx = fmaxf(mx, lg[e]);
    float ex[8], sum = 0.f;
#pragma unroll
    for (int e = 0; e < 8; ++e) { ex[e] = expf(lg[e] - mx); sum += ex[e]; }
#pragma unroll
    for (int e = 0; e < 8; ++e) probs[(long)b * 8 + e] = ex[e] / sum;
    int i0 = 0; float b0 = lg[0];
#pragma unroll
    for (int e = 1; e < 8; ++e) if (lg[e] > b0) { b0 = lg[e]; i0 = e; }
    int i1 = -1; float b1v = -3.4e38f;
#pragma unroll
    for (int e = 0; e < 8; ++e) if (e != i0 && lg[e] > b1v) { b1v = lg[e]; i1 = e; }
    float b2v = -3.4e38f;
#pragma unroll
    for (int e = 0; e < 8; ++e) if (e != i0 && e != i1 && lg[e] > b2v) b2v = lg[e];
    idxg[b * 2 + 0] = i0; idxg[b * 2 + 1] = i1;
    gvg[b * 2 + 0] = ex[i0] / sum; gvg[b * 2 + 1] = ex[i1] / sum;
    if (b1v - b2v < GAP_DELTA) {
      int p = atomicAdd(scount, 1);
      if (p < B_T) suspects[p] = b;
    }
  }
}

// ---------------- exact fp32 recompute for gap-guard suspects ----------------
__global__ __launch_bounds__(256) void router_fixup(const float* __restrict__ x,
                                                    const float* __restrict__ Wr1,
                                                    const float* __restrict__ br1,
                                                    const float* __restrict__ Wr2,
                                                    const float* __restrict__ br2,
                                                    const int* __restrict__ suspects,
                                                    const int* __restrict__ scount,
                                                    float* __restrict__ probs,
                                                    int* __restrict__ idxg,
                                                    float* __restrict__ gvg) {
  __shared__ float xr[IN_D];
  __shared__ float hr[RHD];
  __shared__ float lgs[NEXP];
  const int n = *scount;
  const int tid = threadIdx.x;
  for (int s = blockIdx.x; s < n && s < B_T; s += 128) {
    const int b = suspects[s];
    __syncthreads();
    for (int i = tid; i < IN_D; i += 256) xr[i] = x[(long)b * IN_D + i];
    __syncthreads();
    {
      const int c0 = tid * 2, c1 = tid * 2 + 1;
      const float* w0 = Wr1 + (long)c0 * IN_D;
      const float* w1 = Wr1 + (long)c1 * IN_D;
      float a0 = 0.f, a1 = 0.f;
      for (int k = 0; k < IN_D; ++k) {
        float xv = xr[k];
        a0 = fmaf(xv, w0[k], a0);
        a1 = fmaf(xv, w1[k], a1);
      }
      hr[c0] = fmaxf(a0 + br1[c0], 0.f);
      hr[c1] = fmaxf(a1 + br1[c1], 0.f);
    }
    __syncthreads();
    if (tid < NEXP) {
      const float* w2 = Wr2 + (long)tid * RHD;
      float a = 0.f;
      for (int k = 0; k < RHD; ++k) a = fmaf(hr[k], w2[k], a);
      lgs[tid] = a + br2[tid];
    }
    __syncthreads();
    if (tid == 0) {
      float lg[8];
#pragma unroll
      for (int e = 0; e < 8; ++e) lg[e] = lgs[e];
      float mx = lg[0];
#pragma unroll
      for (int e = 1; e < 8; ++e) mx = fmaxf(mx, lg[e]);
      float ex[8], sum = 0.f;
#pragma unroll
      for (int e = 0; e < 8; ++e) { ex[e] = expf(lg[e] - mx); sum += ex[e]; }
#pragma unroll
      for (int e = 0; e < 8; ++e) probs[(long)b * 8 + e] = ex[e] / sum;
      int i0 = 0; float b0 = lg[0];
#pragma unroll
      for (int e = 1; e < 8; ++e) if (lg[e] > b0) { b0 = lg[e]; i0 = e; }
      int i1 = -1; float b1v = -3.4e38f;
#pragma unroll
      for (int e = 0; e < 8; ++e) if (e != i0 && lg[e] > b1v) { b1v = lg[e]; i1 = e; }
      idxg[b * 2 + 0] = i0; idxg[b * 2 + 1] = i1;
      gvg[b * 2 + 0] = ex[i0] / sum; gvg[b * 2 + 1] = ex[i1] / sum;
    }
  }
}

// ---------------- histogram / scan / placement -------------------------------
__global__ __launch_bounds__(256) void hist_block(const int* __restrict__ idxg,
                                                  int* __restrict__ bc) {
  __shared__ int hloc[NEXP];
  const int t = threadIdx.x;
  if (t < NEXP) hloc[t] = 0;
  __syncthreads();
  int a = blockIdx.x * 256 + t;
  atomicAdd(&hloc[idxg[a]], 1);
  __syncthreads();
  if (t < NEXP) bc[blockIdx.x * NEXP + t] = hloc[t];
}

__global__ void scan_all(const int* __restrict__ bc, int* __restrict__ blockbase,
                         int* __restrict__ ntiles, int* __restrict__ te,
                         int* __restrict__ ts, int* __restrict__ tc,
                         float* __restrict__ loss_out) {
  __shared__ int counts[NEXP], basep[NEXP];
  const int t = threadIdx.x;
  if (t < NEXP) {
    int s = 0;
    for (int b = 0; b < 64; ++b) s += bc[b * NEXP + t];
    counts[t] = s;
  }
  __syncthreads();
  if (t == 0) {
    int acc = 0, nb = 0;
    for (int e = 0; e < NEXP; ++e) {
      basep[e] = acc;
      int c = counts[e];
      int nt = (c + 255) >> 8;
      for (int i = 0; i < nt; ++i) {
        te[nb] = e; ts[nb] = acc + i * 256; tc[nb] = min(256, c - i * 256); ++nb;
      }
      acc += c;
    }
    *ntiles = nb;
    *loss_out = 0.f;
  }
  __syncthreads();
  if (t < NEXP) {
    int run = basep[t];
    for (int b = 0; b < 64; ++b) { blockbase[b * NEXP + t] = run; run += bc[b * NEXP + t]; }
  }
}

__global__ __launch_bounds__(256) void place2(const int* __restrict__ idxg,
                                              const int* __restrict__ blockbase,
                                              int* __restrict__ token_list,
                                              int* __restrict__ slotmap) {
  __shared__ int cur[NEXP];
  const int t = threadIdx.x;
  if (t < NEXP) cur[t] = blockbase[blockIdx.x * NEXP + t];
  __syncthreads();
  int a = blockIdx.x * 256 + t;
  int e = idxg[a];
  int pos = atomicAdd(&cur[e], 1);
  token_list[pos] = a >> 1;
  slotmap[a] = pos;
}

// ---------------- int8 ternary MFMA GEMM (4-phase, bf16 y output) ------------
// R10-verified configuration: 256x256 tile, BK=128 bytes, 8 waves, 128KB LDS,
// counted vmcnt(6), launch_bounds(512,2) -> 128 VGPR, no spill.
template <int KDIM, bool INDIRECT, bool RELU, bool FINAL>
__global__ __launch_bounds__(512, 2) void gemm_i8(
    const int8_t* __restrict__ Aq, const int8_t* __restrict__ Wq,
    const float* __restrict__ swf_layer, const float* __restrict__ rcp_act,
    const float* __restrict__ bias, const int* __restrict__ te,
    const int* __restrict__ ts, const int* __restrict__ tc,
    const int* __restrict__ ntiles_p, const int* __restrict__ token_list,
    void* __restrict__ Yout, int Nvalid) {
  if ((int)blockIdx.y >= *ntiles_p) return;
  extern __shared__ __align__(16) int8_t smem_dyn[];
  const int t = blockIdx.y;
  const int e = te[t], row0 = ts[t], rcount = tc[t];
  const int col0 = blockIdx.x * 256;
  const int tid = threadIdx.x;
  const int lane = tid & 63, wid = tid >> 6;
  const int wsm = wid >> 2, wsn = wid & 3;
  const int fr = lane & 15, hi = lane >> 4;

  const int8_t* sA[2][2];
  const int8_t* sB[2][2];
#pragma unroll
  for (int hh = 0; hh < 2; ++hh)
#pragma unroll
    for (int i = 0; i < 2; ++i) {
      int p = i * 512 + tid;
      int rl = p >> 3, c = p & 7;
      int cs = c ^ (rl & 7);
      int rt = hh * 128 + rl;
      int ar = row0 + min(rt, rcount - 1);
      long arow = INDIRECT ? (long)token_list[ar] : (long)ar;
      sA[hh][i] = Aq + arow * KDIM + cs * 16;
      int br = min(col0 + rt, Nvalid - 1);
      sB[hh][i] = Wq + ((long)e * Nvalid + br) * (long)KDIM + cs * 16;
    }

  auto stage = [&](int buf, int kt, int which) {
    const int hh = which & 1;
    const bool isB = which >= 2;
    const int8_t* p0 = isB ? sB[hh][0] : sA[hh][0];
    const int8_t* p1 = isB ? sB[hh][1] : sA[hh][1];
    int base = buf * 65536 + (isB ? 32768 : 0) + hh * 16384 + wid * 1024;
    load_lds16(p0 + (long)kt * 128, &smem_dyn[base]);
    load_lds16(p1 + (long)kt * 128, &smem_dyn[base + 8192]);
  };

  const int swz0 = ((0 * 4 + hi) ^ (fr & 7)) * 16 + fr * 128;
  const int swz1 = ((1 * 4 + hi) ^ (fr & 7)) * 16 + fr * 128;

  v4i acc[2][2][4][2] = {};
  v4i aF[4][2];
  v4i bF[2][2][2];

  constexpr int KT = KDIM / 128;
  stage(0, 0, 0); stage(0, 0, 1); stage(0, 0, 2); stage(0, 0, 3);
  stage(1, 1, 0); stage(1, 1, 2); stage(1, 1, 1);
  asm volatile("s_waitcnt vmcnt(6)" ::: "memory");
  asm volatile("s_barrier" ::: "memory");

  for (int kt = 0; kt < KT; ++kt) {
    const int buf = kt & 1;
    const int ab = buf * 65536;
    const int bb = ab + 32768;
#pragma unroll
    for (int mi = 0; mi < 4; ++mi) {
      aF[mi][0] = *(const v4i*)&smem_dyn[ab + (wsm * 64 + mi * 16) * 128 + swz0];
      aF[mi][1] = *(const v4i*)&smem_dyn[ab + (wsm * 64 + mi * 16) * 128 + swz1];
    }
#pragma unroll
    for (int ni = 0; ni < 2; ++ni) {
      bF[0][ni][0] = *(const v4i*)&smem_dyn[bb + (wsn * 32 + ni * 16) * 128 + swz0];
      bF[0][ni][1] = *(const v4i*)&smem_dyn[bb + (wsn * 32 + ni * 16) * 128 + swz1];
    }
    if (kt + 1 < KT) stage(buf ^ 1, kt + 1, 3);
    __builtin_amdgcn_s_setprio(1);
#pragma unroll
    for (int mi = 0; mi < 4; ++mi)
#pragma unroll
      for (int ni = 0; ni < 2; ++ni) {
        acc[0][0][mi][ni] = __builtin_amdgcn_mfma_i32_16x16x64_i8(aF[mi][0], bF[0][ni][0], acc[0][0][mi][ni], 0, 0, 0);
        acc[0][0][mi][ni] = __builtin_amdgcn_mfma_i32_16x16x64_i8(aF[mi][1], bF[0][ni][1], acc[0][0][mi][ni], 0, 0, 0);
      }
    __builtin_amdgcn_s_setprio(0);
    asm volatile("s_barrier" ::: "memory");
#pragma unroll
    for (int ni = 0; ni < 2; ++ni) {
      bF[1][ni][0] = *(const v4i*)&smem_dyn[bb + (128 + wsn * 32 + ni * 16) * 128 + swz0];
      bF[1][ni][1] = *(const v4i*)&smem_dyn[bb + (128 + wsn * 32 + ni * 16) * 128 + swz1];
    }
    if (kt + 2 < KT) stage(buf, kt + 2, 0);
    __builtin_amdgcn_s_setprio(1);
#pragma unroll
    for (int mi = 0; mi < 4; ++mi)
#pragma unroll
      for (int ni = 0; ni < 2; ++ni) {
        acc[0][1][mi][ni] = __builtin_amdgcn_mfma_i32_16x16x64_i8(aF[mi][0], bF[1][ni][0], acc[0][1][mi][ni], 0, 0, 0);
        acc[0][1][mi][ni] = __builtin_amdgcn_mfma_i32_16x16x64_i8(aF[mi][1], bF[1][ni][1], acc[0][1][mi][ni], 0, 0, 0);
      }
    __builtin_amdgcn_s_setprio(0);
    asm volatile("s_barrier" ::: "memory");
#pragma unroll
    for (int mi = 0; mi < 4; ++mi) {
      aF[mi][0] = *(const v4i*)&smem_dyn[ab + (128 + wsm * 64 + mi * 16) * 128 + swz0];
      aF[mi][1] = *(const v4i*)&smem_dyn[ab + (128 + wsm * 64 + mi * 16) * 128 + swz1];
    }
    if (kt + 2 < KT) stage(buf, kt + 2, 2);
    __builtin_amdgcn_s_setprio(1);
#pragma unroll
    for (int mi = 0; mi < 4; ++mi)
#pragma unroll
      for (int ni = 0; ni < 2; ++ni) {
        acc[1][0][mi][ni] = __builtin_amdgcn_mfma_i32_16x16x64_i8(aF[mi][0], bF[0][ni][0], acc[1][0][mi][ni], 0, 0, 0);
        acc[1][0][mi][ni] = __builtin_amdgcn_mfma_i32_16x16x64_i8(aF[mi][1], bF[0][ni][1], acc[1][0][mi][ni], 0, 0, 0);
      }
    __builtin_amdgcn_s_setprio(0);
    asm volatile("s_barrier" ::: "memory");
    if (kt + 2 < KT) stage(buf, kt + 2, 1);
    __builtin_amdgcn_s_setprio(1);
#pragma unroll
    for (int mi = 0; mi < 4; ++mi)
#pragma unroll
      for (int ni = 0; ni < 2; ++ni) {
        acc[1][1][mi][ni] = __builtin_amdgcn_mfma_i32_16x16x64_i8(aF[mi][0], bF[1][ni][0], acc[1][1][mi][ni], 0, 0, 0);
        acc[1][1][mi][ni] = __builtin_amdgcn_mfma_i32_16x16x64_i8(aF[mi][1], bF[1][ni][1], acc[1][1][mi][ni], 0, 0, 0);
      }
    __builtin_amdgcn_s_setprio(0);
    if (kt < KT - 3) {
      asm volatile("s_waitcnt vmcnt(6)" ::: "memory");
    } else {
      asm volatile("s_waitcnt vmcnt(0)" ::: "memory");
    }
    asm volatile("s_barrier" ::: "memory");
  }

  const float sw = swf_layer[e];
  const int rbase = hi * 4;
  const float* bias_e = bias + (long)e * Nvalid;
#pragma unroll
  for (int qm = 0; qm < 2; ++qm)
#pragma unroll
    for (int mi = 0; mi < 4; ++mi)
#pragma unroll
      for (int rg = 0; rg < 4; ++rg) {
        int trow = qm * 128 + wsm * 64 + mi * 16 + rbase + rg;
        if (trow >= rcount) continue;
        int slot = row0 + trow;
        float rcp = rcp_act[INDIRECT ? token_list[slot] : slot];
        float dq = sw * rcp;
        if constexpr (!FINAL) {
          uint16_t* yrow = (uint16_t*)Yout + (long)slot * 2048;
#pragma unroll
          for (int qn = 0; qn < 2; ++qn)
#pragma unroll
            for (int ni = 0; ni < 2; ++ni) {
              int o = col0 + qn * 128 + wsn * 32 + ni * 16 + fr;
              float v = (float)acc[qm][qn][mi][ni][rg] * dq + bias_e[o];
              if (RELU) v = fmaxf(v, 0.f);
              yrow[o] = f2bf(v);
            }
        } else {
          float* zrow = (float*)Yout + (long)slot * 1024;
#pragma unroll
          for (int qn = 0; qn < 2; ++qn)
#pragma unroll
            for (int ni = 0; ni < 2; ++ni) {
              int o = col0 + qn * 128 + wsn * 32 + ni * 16 + fr;
              float bb2 = bias_e[min(o, Nvalid - 1)];
              zrow[o] = (float)acc[qm][qn][mi][ni][rg] * dq + bb2;
            }
        }
      }
}

// ---------------- gate-weighted combine --------------------------------------
__global__ __launch_bounds__(256) void combine(const float* __restrict__ z,
                                               const int* __restrict__ slotmap,
                                               const float* __restrict__ gvg,
                                               float* __restrict__ out) {
  const int b = blockIdx.x;
  const int c = threadIdx.x;
  if (c >= 250) return;
  const int s0 = slotmap[b * 2], s1 = slotmap[b * 2 + 1];
  const float g0 = gvg[b * 2] * 0.5f, g1 = gvg[b * 2 + 1] * 0.5f;
  float4 a = *(const float4*)(z + (long)s0 * 1024 + c * 4);
  float4 q = *(const float4*)(z + (long)s1 * 1024 + c * 4);
  float4 o = {g0 * a.x + g1 * q.x, g0 * a.y + g1 * q.y,
              g0 * a.z + g1 * q.z, g0 * a.w + g1 * q.w};
  *(float4*)(out + (long)b * CDIM + c * 4) = o;
}

// ---------------- host launcher ----------------------------------------------
extern "C" void kernel_launch(void* const* d_in, const int* in_sizes, int n_in,
                              void* d_out, int out_size, void* d_ws, size_t ws_size,
                              hipStream_t stream) {
  const float* x   = (const float*)d_in[0];
  const float* Wr1 = (const float*)d_in[1];
  const float* br1 = (const float*)d_in[2];
  const float* Wr2 = (const float*)d_in[3];
  const float* br2 = (const float*)d_in[4];
  const float* W1  = (const float*)d_in[5];
  const float* b1  = (const float*)d_in[6];
  const float* W2  = (const float*)d_in[7];
  const float* b2  = (const float*)d_in[8];
  const float* W3  = (const float*)d_in[9];
  const float* b3  = (const float*)d_in[10];
  float* out = (float*)d_out;
  char* ws = (char*)d_ws;

  size_t off = 0;
  auto alloc = [&](size_t sz) { size_t r = off; off = (off + sz + 255) & ~(size_t)255; return r; };
  size_t O_META  = alloc(8192);
  size_t O_SUSP  = alloc(B_T * sizeof(int));
  size_t O_PART  = alloc(24 * 64 * sizeof(double));
  size_t O_SWF   = alloc(24 * sizeof(float));
  size_t O_RCPX  = alloc(B_T * sizeof(float));
  size_t O_IDX   = alloc(B_T * 2 * sizeof(int));
  size_t O_GVG   = alloc(B_T * 2 * sizeof(float));
  size_t O_TLIST = alloc(NSLOT * sizeof(int));
  size_t O_SLOT  = alloc(B_T * 2 * sizeof(int));
  size_t O_S1    = alloc(NSLOT * sizeof(float));
  size_t O_S2    = alloc(NSLOT * sizeof(float));
  size_t O_XQ    = alloc((size_t)B_T * IN_D);
  size_t O_WQ1   = alloc((size_t)NEXP * H1D * IN_D);
  size_t O_WQ2   = alloc((size_t)NEXP * H2D * H1D);
  size_t O_WQ3   = alloc((size_t)NEXP * CDIM * H2D);
  size_t O_YQ    = alloc((size_t)NSLOT * 2048);
  size_t O_YBIG  = alloc((size_t)NSLOT * 2048 * sizeof(float));
  (void)ws_size; (void)in_sizes; (void)n_in;

  int*    te     = (int*)(ws + O_META);
  int*    tsv    = te + 144;
  int*    tcv    = tsv + 144;
  int*    ntiles = tcv + 144;
  int*    bc     = ntiles + 4;
  int*    bbase  = bc + 512;
  int*    scount = bbase + 512;
  int*    susp   = (int*)(ws + O_SUSP);
  double* part   = (double*)(ws + O_PART);
  float*  swf    = (float*)(ws + O_SWF);
  float*  rcpx   = (float*)(ws + O_RCPX);
  int*    idxg   = (int*)(ws + O_IDX);
  float*  gvg    = (float*)(ws + O_GVG);
  int*    tlist  = (int*)(ws + O_TLIST);
  int*    slotmap= (int*)(ws + O_SLOT);
  float*  s1     = (float*)(ws + O_S1);
  float*  s2     = (float*)(ws + O_S2);
  int8_t* Xq     = (int8_t*)(ws + O_XQ);
  int8_t* wq1    = (int8_t*)(ws + O_WQ1);
  int8_t* wq2    = (int8_t*)(ws + O_WQ2);
  int8_t* wq3    = (int8_t*)(ws + O_WQ3);
  float*  Ybig   = (float*)(ws + O_YBIG);   // router h (fp32); y (bf16); z (fp32)
  float*  h      = Ybig;
  uint16_t* ybf  = (uint16_t*)Ybig;
  float*  zbuf   = Ybig;
  int8_t* Yq     = (int8_t*)(ws + O_YQ);

  char* ybytes = (char*)Ybig;
  uint16_t* xh = (uint16_t*)(ybytes + (80l << 20));
  uint16_t* xl = (uint16_t*)(ybytes + (97l << 20));
  uint16_t* wh = (uint16_t*)(ybytes + (114l << 20));
  uint16_t* wl = (uint16_t*)(ybytes + (116l << 20));

  hipMemsetAsync(ws + O_META, 0, 8192, stream);

  // weight scales + ternary quant (ILP-4)
  wabs_all<<<dim3(64, 24), 256, 0, stream>>>(W1, W2, W3, part);
  finalize_scales<<<1, 64, 0, stream>>>(part, swf);
  wquant_all<<<dim3(64, 24), 256, 0, stream>>>(W1, W2, W3, wq1, wq2, wq3, swf);

  // x: fused quant + split; Wr1 split
  actquant_split<<<B_T, 256, 0, stream>>>(x, Xq, rcpx, xh, xl);
  split_bf16<<<512, 256, 0, stream>>>(Wr1, wh, wl, (long)RHD * IN_D / 4);

  // router
  router_mfma<<<dim3(B_T / 128, RHD / 128), 256, 0, stream>>>(xh, xl, wh, wl, br1, h);
  router_stage2<<<B_T / 4, 256, 0, stream>>>(h, Wr2, br2, out + (size_t)B_T * CDIM,
                                             idxg, gvg, scount, susp);
  router_fixup<<<128, 256, 0, stream>>>(x, Wr1, br1, Wr2, br2, susp, scount,
                                        out + (size_t)B_T * CDIM, idxg, gvg);
  hist_block<<<64, 256, 0, stream>>>(idxg, bc);
  scan_all<<<1, 64, 0, stream>>>(bc, bbase, ntiles, te, tsv, tcv,
                                 out + (size_t)B_T * CDIM + (size_t)B_T * NEXP);
  place2<<<64, 256, 0, stream>>>(idxg, bbase, tlist, slotmap);

  // expert layers (int8 MFMA; BK=128, 128KB LDS, launch_bounds(512,2); y bf16)
  gemm_i8<IN_D, true, true, false><<<dim3(H1D / 256, MAXT), 512, 131072, stream>>>(
      Xq, wq1, swf + 0, rcpx, b1, te, tsv, tcv, ntiles, tlist, (void*)ybf, H1D);
  actquant_y<<<NSLOT, 256, 0, stream>>>(ybf, Yq, s1);
  gemm_i8<2048, false, true, false><<<dim3(H2D / 256, MAXT), 512, 131072, stream>>>(
      Yq, wq2, swf + 8, s1, b2, te, tsv, tcv, ntiles, tlist, (void*)ybf, H2D);
  actquant_y<<<NSLOT, 256, 0, stream>>>(ybf, Yq, s2);
  gemm_i8<2048, false, false, true><<<dim3(1024 / 256, MAXT), 512, 131072, stream>>>(
      Yq, wq3, swf + 16, s2, b3, te, tsv, tcv, ntiles, tlist, (void*)zbuf, CDIM);

  // gate-weighted combine into d_out
  combine<<<B_T, 256, 0, stream>>>(zbuf, slotmap, gvg, out);
}